// Round 1
// baseline (197.107 us; speedup 1.0000x reference)
//
#include <hip/hip_runtime.h>
#include <hip/hip_bf16.h>

// fp32 I/O, fp16 MFMA compute (verified: absmax 3.9e-3 vs thr 3.1e-2).
// R12: attn restructured to 4 waves x 32 q-rows (2 sw x 2 hf), 256 thr/block.
//      kf/vf LDS tile reads are shared across 2 q-sets per wave -> LDS wave-ops
//      per 64q x 64k block-iter drop 240 -> 144 (kernel was ~83% LDS-pipe
//      bound). Om merge buffer aliased over Ks (union) to keep 2 blocks/CU.
//      Grid/split-K/pairing/swizzles/softmax identical to R11.

typedef __attribute__((ext_vector_type(8))) _Float16 vhalf8;
typedef __attribute__((ext_vector_type(4))) _Float16 vhalf4;
typedef __attribute__((ext_vector_type(4))) float vfloat4;

#define D_MODEL 1024
#define SEQ     2048
#define NB      2
#define NH      16
#define HD      64

// softmax: exp(s/8) = exp2(s * 0.125*log2(e)); constant offset cancels in o/l.
#define SCALE_K1 0.18033688f

__device__ __forceinline__ void async16(const void* g, void* l) {
  __builtin_amdgcn_global_load_lds(
      (const __attribute__((address_space(1))) unsigned int*)g,
      (__attribute__((address_space(3))) unsigned int*)l, 16, 0, 0);
}

// ---------------------------------------------------------------------------
// prep: z<4 -> weight transpose+convert planes; z==4 -> x fp32->fp16 convert.
// ---------------------------------------------------------------------------
__global__ __launch_bounds__(256) void prep(
    const float* __restrict__ x,
    const float* __restrict__ Wq, const float* __restrict__ Wk,
    const float* __restrict__ Wv, const float* __restrict__ Wo,
    _Float16* __restrict__ Xh, _Float16* __restrict__ Wt_qkv,
    _Float16* __restrict__ Wot) {
  int z = blockIdx.z;
  int t = threadIdx.x;
  if (z == 4) {
    int id = blockIdx.y * 16 + blockIdx.x;
#pragma unroll
    for (int pass = 0; pass < 8; pass++) {
      size_t i = ((size_t)(pass * 256 + id) * 256 + t) * 8;
      float4 a = *(const float4*)&x[i];
      float4 b = *(const float4*)&x[i + 4];
      vhalf8 h;
      h[0] = (_Float16)a.x; h[1] = (_Float16)a.y;
      h[2] = (_Float16)a.z; h[3] = (_Float16)a.w;
      h[4] = (_Float16)b.x; h[5] = (_Float16)b.y;
      h[6] = (_Float16)b.z; h[7] = (_Float16)b.w;
      *(vhalf8*)&Xh[i] = h;
    }
    return;
  }
  __shared__ _Float16 tile[64][65];
  const float* in = (z == 0) ? Wq : (z == 1) ? Wk : (z == 2) ? Wv : Wo;
  _Float16* out = (z < 3) ? (Wt_qkv + (size_t)z * 1024 * 1024) : Wot;
  int c0 = blockIdx.x * 64, r0 = blockIdx.y * 64;
  int tc = t & 63, tr = t >> 6;
#pragma unroll
  for (int p = 0; p < 16; p++) {
    int r = tr + p * 4;
    tile[r][tc] = (_Float16)in[(size_t)(r0 + r) * 1024 + c0 + tc];
  }
  __syncthreads();
#pragma unroll
  for (int p = 0; p < 16; p++) {
    int r = tr + p * 4;
    out[(size_t)(c0 + r) * 1024 + r0 + tc] = tile[tc][r];
  }
}

// ---------------------------------------------------------------------------
// m97-style f16 GEMM: C[M][N] = A[M][K] @ Bt[N][K]^T.
// 128xBN tile, 4 waves, BK=32, global_load_lds width-16, XOR slot swizzle.
// mode 0: f16 out.  mode 1: f32 out.  mode 2 (QKV): f16 out, V cols
// (n >= 2048) written transposed into Vt[(b,h)][d][s] (packed 8B stores).
// ---------------------------------------------------------------------------
template <int BN>
__global__ __launch_bounds__(256) void gemm128(
    const _Float16* __restrict__ A, const _Float16* __restrict__ Bt,
    _Float16* __restrict__ Ch, float* __restrict__ Cf,
    _Float16* __restrict__ Vt, int M, int N, int K, int mode) {
  constexpr int ACH = 8;
  constexpr int BCH = BN / 16;
  constexpr int CPW = (ACH + BCH) / 4;
  constexpr int JN = BN / 32;
  __shared__ _Float16 As[128 * 32];
  __shared__ _Float16 Bs[BN * 32];
  int m0 = blockIdx.x * 128, n0 = blockIdx.y * BN;
  int t = threadIdx.x;
  int lane = t & 63, wave = t >> 6;
  int wm = (wave >> 1) * 64, wn = (wave & 1) * (BN / 2);
  int col = lane & 15, quad = lane >> 4;
  int srow = lane >> 2;
  int gcol = (((lane & 3) ^ (srow & 3)) << 3);

  vfloat4 acc[4][JN];
#pragma unroll
  for (int i = 0; i < 4; i++)
#pragma unroll
    for (int j = 0; j < JN; j++) {
      acc[i][j][0] = 0.f; acc[i][j][1] = 0.f;
      acc[i][j][2] = 0.f; acc[i][j][3] = 0.f;
    }

  int xq = (quad ^ (col & 3)) * 8;

  for (int k0 = 0; k0 < K; k0 += 32) {
    __syncthreads();
#pragma unroll
    for (int j = 0; j < CPW; j++) {
      int c = wave * CPW + j;
      if (c < ACH) {
        int row = c * 16 + srow;
        async16(&A[(size_t)(m0 + row) * K + k0 + gcol], &As[c * 512]);
      } else {
        int row = (c - ACH) * 16 + srow;
        async16(&Bt[(size_t)(n0 + row) * K + k0 + gcol], &Bs[(c - ACH) * 512]);
      }
    }
    __syncthreads();

    vhalf8 af[4], bf[JN];
#pragma unroll
    for (int i = 0; i < 4; i++)
      af[i] = *(const vhalf8*)&As[(wm + i * 16 + col) * 32 + xq];
#pragma unroll
    for (int j = 0; j < JN; j++)
      bf[j] = *(const vhalf8*)&Bs[(wn + j * 16 + col) * 32 + xq];
#pragma unroll
    for (int i = 0; i < 4; i++)
#pragma unroll
      for (int j = 0; j < JN; j++)
        acc[i][j] = __builtin_amdgcn_mfma_f32_16x16x32_f16(af[i], bf[j], acc[i][j], 0, 0, 0);
  }

  bool vmode = (mode == 2) && (n0 >= 2048);
#pragma unroll
  for (int i = 0; i < 4; i++)
#pragma unroll
    for (int j = 0; j < JN; j++) {
      if (vmode) {
        // transposed V write: r=0..3 are consecutive ss -> one 8B store
        int n = n0 + wn + j * 16 + col;
        int nn = n - 2048;
        int hh = nn >> 6, dd = nn & 63;
        int m_base = m0 + wm + i * 16 + quad * 4;
        int bb = m_base >> 11, ss = m_base & 2047;
        vhalf4 pk;
        pk[0] = (_Float16)acc[i][j][0]; pk[1] = (_Float16)acc[i][j][1];
        pk[2] = (_Float16)acc[i][j][2]; pk[3] = (_Float16)acc[i][j][3];
        *(vhalf4*)&Vt[(((size_t)bb * NH + hh) * HD + dd) * SEQ + ss] = pk;
      } else {
#pragma unroll
        for (int r = 0; r < 4; r++) {
          int m = m0 + wm + i * 16 + quad * 4 + r;
          int n = n0 + wn + j * 16 + col;
          if (mode == 1)
            Cf[(size_t)m * N + n] = acc[i][j][r];
          else
            Ch[(size_t)m * N + n] = (_Float16)acc[i][j][r];
        }
      }
    }
}

// ---------------------------------------------------------------------------
// Flash attention, causal, fixed-offset softmax, IN-BLOCK SPLIT-K.
// 4 waves (256 thr)/block: half hf = wave>>1 processes alternate 64-key
// tiles (own Ks/Vs buffer); sub-wave sw = wave&1 owns 32 q-rows (2 q-sets
// of 16). kf/vf LDS tile reads are shared across both q-sets -> halves the
// dominant LDS traffic. Partial (o, l) merged through LDS (exact: fixed
// offset is order-independent). Two phases per block: q-tiles {31-pp, pp}
// -> exactly 17 iters for all blocks. Grid 512 = 2 blocks/CU.
// Om merge buffer aliases Ks (dead during merge); extra barrier per phase.
// ---------------------------------------------------------------------------
__global__ __launch_bounds__(256, 2) void attn(
    const _Float16* __restrict__ QKV, const _Float16* __restrict__ Vt,
    _Float16* __restrict__ Vec) {
  int blk = blockIdx.x;
  int pp = blk >> 5;            // 0..15
  int hb = blk & 31;
  int h = hb & 15;
  int b = hb >> 4;

  const _Float16* Qb  = QKV + (size_t)(b * SEQ) * 3072 + h * HD;
  const _Float16* Kb  = QKV + (size_t)(b * SEQ) * 3072 + 1024 + h * HD;
  const _Float16* Vtb = Vt + (size_t)(b * NH + h) * HD * SEQ;

  int t = threadIdx.x;
  int lane = t & 63, wave = t >> 6;
  int sw = wave & 1, hf = wave >> 1;
  int col = lane & 15, quad = lane >> 4;

  __shared__ union {
    _Float16 Ks[2][64][72];     // 18432 B
    float    Om[64][65];        // 16640 B (merge epilogue only; Ks dead then)
  } su;
  __shared__ _Float16 Vs[2][64][72];
  __shared__ _Float16 Ps[4][32][72];
  __shared__ float Lm[64];

  // staging: 128 threads per half; each thread covers rows srow and srow+32
  int tl = t & 127;
  int srow = tl >> 2;                            // 0..31
  int scol = (tl & 3) * 16;
  int kslotA = ((srow & 3) << 4) + (srow >> 2);  // K row permutation, row srow
  int kslotB = kslotA + 8;                       // row srow+32: (srow>>2)+8
  int kcol = scol ^ ((srow & 3) << 4);           // XOR bank swizzle (same both)

  int tiles[2] = {31 - pp, pp};

  // prologue: prefetch this half's first tile of phase 0 (ti = hf)
  vhalf8 krA0, krA1, krB0, krB1, vrA0, vrA1, vrB0, vrB1;
  {
    const _Float16* kg = &Kb[(size_t)(hf * 64 + srow) * 3072 + scol];
    krA0 = *(const vhalf8*)kg; krA1 = *(const vhalf8*)(kg + 8);
    kg += (size_t)32 * 3072;
    krB0 = *(const vhalf8*)kg; krB1 = *(const vhalf8*)(kg + 8);
    const _Float16* vg = &Vtb[(size_t)srow * SEQ + hf * 64 + scol];
    vrA0 = *(const vhalf8*)vg; vrA1 = *(const vhalf8*)(vg + 8);
    vg += (size_t)32 * SEQ;
    vrB0 = *(const vhalf8*)vg; vrB1 = *(const vhalf8*)(vg + 8);
  }

#pragma unroll
  for (int phase = 0; phase < 2; phase++) {
    int qt = tiles[phase];
    int q0 = qt * 64;
    int ntk = qt + 1;            // key tiles for this q-tile
    int J = (ntk + 1) >> 1;      // block-uniform loop count
    int wq0 = q0 + sw * 32;      // this wave's 32 q-rows

    // Q fragments (2 q-sets), pre-scaled so softmax is bare exp2(s)
    vhalf8 qf0[2], qf1[2];
#pragma unroll
    for (int qs = 0; qs < 2; qs++) {
      const _Float16* qp = &Qb[(size_t)(wq0 + qs * 16 + col) * 3072 + quad * 8];
      qf0[qs] = *(const vhalf8*)qp;
      qf1[qs] = *(const vhalf8*)(qp + 32);
#pragma unroll
      for (int i = 0; i < 8; i++) {
        qf0[qs][i] = qf0[qs][i] * (_Float16)SCALE_K1;
        qf1[qs][i] = qf1[qs][i] * (_Float16)SCALE_K1;
      }
    }

    vfloat4 o[2][4];
#pragma unroll
    for (int qs = 0; qs < 2; qs++)
#pragma unroll
      for (int i = 0; i < 4; i++) {
        o[qs][i][0] = 0.f; o[qs][i][1] = 0.f;
        o[qs][i][2] = 0.f; o[qs][i][3] = 0.f;
      }
    float lsum[2][4] = {{0.f, 0.f, 0.f, 0.f}, {0.f, 0.f, 0.f, 0.f}};

    for (int j = 0; j < J; j++) {
      int ti = 2 * j + hf;
      bool active = (ti < ntk);
      int kb = ti * 64;
      if (active) {
        *(vhalf8*)&su.Ks[hf][kslotA][kcol]     = krA0;
        *(vhalf8*)&su.Ks[hf][kslotA][kcol + 8] = krA1;
        *(vhalf8*)&su.Ks[hf][kslotB][kcol]     = krB0;
        *(vhalf8*)&su.Ks[hf][kslotB][kcol + 8] = krB1;
        *(vhalf8*)&Vs[hf][srow][scol]          = vrA0;
        *(vhalf8*)&Vs[hf][srow][scol + 8]      = vrA1;
        *(vhalf8*)&Vs[hf][srow + 32][scol]     = vrB0;
        *(vhalf8*)&Vs[hf][srow + 32][scol + 8] = vrB1;
      }
      __syncthreads();

      // prefetch this half's next tile (phase-aware), overlaps compute
      {
        int tnext;
        if (phase == 0)
          tnext = (ti + 2 < ntk) ? (ti + 2) : hf;  // else: phase 1's first
        else
          tnext = (ti + 2 < ntk) ? (ti + 2) : ti;  // dead reload, harmless
        int kpf = tnext * 64;
        const _Float16* kg = &Kb[(size_t)(kpf + srow) * 3072 + scol];
        krA0 = *(const vhalf8*)kg; krA1 = *(const vhalf8*)(kg + 8);
        kg += (size_t)32 * 3072;
        krB0 = *(const vhalf8*)kg; krB1 = *(const vhalf8*)(kg + 8);
        const _Float16* vg = &Vtb[(size_t)srow * SEQ + kpf + scol];
        vrA0 = *(const vhalf8*)vg; vrA1 = *(const vhalf8*)(vg + 8);
        vg += (size_t)32 * SEQ;
        vrB0 = *(const vhalf8*)vg; vrB1 = *(const vhalf8*)(vg + 8);
      }

      if (active) {
        // K fragments: loaded ONCE, shared by both q-sets
        vhalf8 kf[4][2];
#pragma unroll
        for (int hh = 0; hh < 4; hh++) {
          int swz = hh << 4;
          kf[hh][0] = *(const vhalf8*)&su.Ks[hf][hh * 16 + col][(quad * 8) ^ swz];
          kf[hh][1] = *(const vhalf8*)&su.Ks[hf][hh * 16 + col][(32 + quad * 8) ^ swz];
        }
        // QK^T + softmax + P-store per q-set
#pragma unroll
        for (int qs = 0; qs < 2; qs++) {
          int wq = wq0 + qs * 16;
          vfloat4 s[4];
#pragma unroll
          for (int hh = 0; hh < 4; hh++) {
            vfloat4 z; z[0]=0.f; z[1]=0.f; z[2]=0.f; z[3]=0.f;
            z = __builtin_amdgcn_mfma_f32_16x16x32_f16(qf0[qs], kf[hh][0], z, 0, 0, 0);
            z = __builtin_amdgcn_mfma_f32_16x16x32_f16(qf1[qs], kf[hh][1], z, 0, 0, 0);
            s[hh] = z;
          }
          bool diag = (kb + 63 > wq);
#pragma unroll
          for (int r = 0; r < 4; r++) {
            int q = wq + quad * 4 + r;
            float p[4];
#pragma unroll
            for (int hh = 0; hh < 4; hh++) {
              float sc = s[hh][r];
              if (diag && (kb + 4 * col + hh > q)) sc = -1e30f;
              p[hh] = __builtin_exp2f(sc);
            }
            lsum[qs][r] += (p[0] + p[1]) + (p[2] + p[3]);
            vhalf4 ph;
            ph[0] = (_Float16)p[0]; ph[1] = (_Float16)p[1];
            ph[2] = (_Float16)p[2]; ph[3] = (_Float16)p[3];
            *(vhalf4*)&Ps[wave][qs * 16 + quad * 4 + r][4 * col] = ph;
          }
        }
        // P write->read is wave-local; LDS drain only
        __asm__ __volatile__("s_waitcnt lgkmcnt(0)" ::: "memory");
        vhalf8 pf0[2], pf1[2];
#pragma unroll
        for (int qs = 0; qs < 2; qs++) {
          pf0[qs] = *(const vhalf8*)&Ps[wave][qs * 16 + col][quad * 8];
          pf1[qs] = *(const vhalf8*)&Ps[wave][qs * 16 + col][32 + quad * 8];
        }
        // PV: vf loaded ONCE per tt, shared by both q-sets
#pragma unroll
        for (int tt = 0; tt < 4; tt++) {
          vhalf8 vf0 = *(const vhalf8*)&Vs[hf][tt * 16 + col][quad * 8];
          vhalf8 vf1 = *(const vhalf8*)&Vs[hf][tt * 16 + col][32 + quad * 8];
#pragma unroll
          for (int qs = 0; qs < 2; qs++) {
            o[qs][tt] = __builtin_amdgcn_mfma_f32_16x16x32_f16(pf0[qs], vf0, o[qs][tt], 0, 0, 0);
            o[qs][tt] = __builtin_amdgcn_mfma_f32_16x16x32_f16(pf1[qs], vf1, o[qs][tt], 0, 0, 0);
          }
        }
      }
      __syncthreads();
    }

    // merge halves: half 1 -> LDS (Om aliases Ks: all tile reads done),
    // half 0 adds + normalizes + writes
    float rs[2][4];
#pragma unroll
    for (int qs = 0; qs < 2; qs++)
#pragma unroll
      for (int r = 0; r < 4; r++) {
        float v = lsum[qs][r];
#pragma unroll
        for (int msk = 1; msk < 16; msk <<= 1) v += __shfl_xor(v, msk, 64);
        rs[qs][r] = v;
      }
    if (hf == 1) {
#pragma unroll
      for (int qs = 0; qs < 2; qs++) {
#pragma unroll
        for (int tt = 0; tt < 4; tt++)
#pragma unroll
          for (int r = 0; r < 4; r++)
            su.Om[sw * 32 + qs * 16 + quad * 4 + r][tt * 16 + col] = o[qs][tt][r];
        if (col == 0)
#pragma unroll
          for (int r = 0; r < 4; r++)
            Lm[sw * 32 + qs * 16 + quad * 4 + r] = rs[qs][r];
      }
    }
    __syncthreads();
    if (hf == 0) {
#pragma unroll
      for (int qs = 0; qs < 2; qs++) {
        float inv_l[4];
#pragma unroll
        for (int r = 0; r < 4; r++)
          inv_l[r] = 1.0f / (rs[qs][r] + Lm[sw * 32 + qs * 16 + quad * 4 + r]);
#pragma unroll
        for (int tt = 0; tt < 4; tt++)
#pragma unroll
          for (int r = 0; r < 4; r++) {
            int q = wq0 + qs * 16 + quad * 4 + r;
            int d = tt * 16 + col;
            float ov = o[qs][tt][r] +
                       su.Om[sw * 32 + qs * 16 + quad * 4 + r][tt * 16 + col];
            Vec[(size_t)(b * SEQ + q) * D_MODEL + h * HD + d] =
                (_Float16)(ov * inv_l[r]);
          }
      }
    }
    __syncthreads();   // protect Om (=Ks) before next phase's staging writes
  }
}

// ---------------------------------------------------------------------------
extern "C" void kernel_launch(void* const* d_in, const int* in_sizes, int n_in,
                              void* d_out, int out_size, void* d_ws, size_t ws_size,
                              hipStream_t stream) {
  const float* x  = (const float*)d_in[0];
  const float* Wq = (const float*)d_in[1];
  const float* Wk = (const float*)d_in[2];
  const float* Wv = (const float*)d_in[3];
  const float* Wo = (const float*)d_in[4];
  float* out = (float*)d_out;

  char* ws = (char*)d_ws;
  _Float16* Xh     = (_Float16*)ws;                    // [4096][1024]   8 MiB
  _Float16* Wt_qkv = (_Float16*)(ws + 8388608);        // [3072][1024]   6 MiB
  _Float16* Wot    = (_Float16*)(ws + 14680064);       // [1024][1024]   2 MiB
  _Float16* QKV    = (_Float16*)(ws + 16777216);       // [4096][3072]  24 MiB (V region unused)
  _Float16* Vt     = (_Float16*)(ws + 41943040);       // [32][64][2048] 8 MiB
  _Float16* Vec    = (_Float16*)(ws + 50331648);       // [4096][1024]   8 MiB

  dim3 tb(256);
  prep<<<dim3(16, 16, 5), tb, 0, stream>>>(x, Wq, Wk, Wv, Wo, Xh, Wt_qkv, Wot);
  gemm128<128><<<dim3(32, 24), tb, 0, stream>>>(Xh, Wt_qkv, QKV, nullptr, Vt,
                                                4096, 3072, 1024, 2);
  attn<<<dim3(512), dim3(256), 0, stream>>>(QKV, Vt, Vec);
  gemm128<64><<<dim3(32, 16), tb, 0, stream>>>(Vec, Wot, nullptr, out, nullptr,
                                               4096, 1024, 1024, 1);
}